// Round 4
// baseline (39.467 us; speedup 1.0000x reference)
//
#include <hip/hip_runtime.h>
#include <math.h>

#define LN2 0.6931471805599453f
#define C0  (-1.1447298858494002f)   // log(2) - log(2*pi)

__device__ __forceinline__ float flog2(float x) { return __builtin_amdgcn_logf(x); }
__device__ __forceinline__ float frcp(float x)  { return __builtin_amdgcn_rcpf(x); }

// log_prob for one row given m=(m0,m1), x=(x0,x1), L=[[a,0],[c,b]]
__device__ __forceinline__ float row_logprob(float m0, float m1, float x0, float x1,
                                             float a, float c, float b) {
    float ra = frcp(a), rb = frcp(b);
    // Cholesky solves: y = L^-1 m, w = L^-1 x
    float y0 = m0 * ra, y1 = (m1 - c * y0) * rb;
    float w0 = x0 * ra, w1 = (x1 - c * w0) * rb;
    float mSm = fmaf(y0, y0, y1 * y1);
    float xSx = fmaf(w0, w0, w1 * w1);
    float xSm = fmaf(w0, y0, w1 * y1);
    float ap = 2.0f + mSm;
    float z  = __builtin_amdgcn_sqrtf(ap * xSx);

    float l2ab = flog2(a) + flog2(b);       // 0.5*log2(det) = log2 a + log2 b
    float l2x  = flog2(xSx);
    float l2p  = flog2(ap);

    // ---- small branch (z <= 2), args clamped like the reference ----
    float zs = fminf(z, 2.0f);
    float t = zs * (1.0f / 3.75f); t *= t;
    float i1 = zs * fmaf(t, fmaf(t, fmaf(t, fmaf(t, fmaf(t, fmaf(t,
               0.00032411f, 0.00301532f), 0.02658733f), 0.15084934f),
               0.51498869f), 0.87890594f), 0.5f);
    float u = 0.5f * zs; u *= u;
    float ps = fmaf(u, fmaf(u, fmaf(u, fmaf(u, fmaf(u, fmaf(u,
               -0.00004686f, -0.00110404f), -0.01919402f), -0.18156897f),
               -0.67278579f), 0.15443144f), 1.0f);
    // ln(z/2) = ln2*(log2 z - 1), log2 z = 0.5*(l2p + l2x)
    float lnz_half = LN2 * fmaf(0.5f, l2p + l2x, -1.0f);
    float k1s = lnz_half * i1 + ps * frcp(zs);
    float lpS = LN2 * (l2ab + 0.5f * l2x - 0.5f * l2p + flog2(k1s));

    // ---- large branch (z > 2): -z - 0.5 ln z + ln(poly_l) merged ----
    float zl = fmaxf(z, 2.0f);
    float v = 2.0f * frcp(zl);
    float pl = fmaf(v, fmaf(v, fmaf(v, fmaf(v, fmaf(v, fmaf(v,
               -0.00068245f, 0.00325614f), -0.00780353f), 0.01504268f),
               -0.03655620f), 0.23498619f), 1.25331414f);
    float lpL = -z + LN2 * (l2ab + 0.25f * l2x - 0.75f * l2p + flog2(pl));

    float lp = (z <= 2.0f) ? lpS : lpL;
    return xSm + lp + C0;
}

// Strided 4 rows/thread: thread i handles rows {i, i+T, i+2T, i+3T}.
// Every load is perfectly lane-coalesced (float2 = 8 B/lane, float4 = 16 B/lane).
__global__ __launch_bounds__(256) void galnll_kernel(
        const float* __restrict__ m, const float* __restrict__ L,
        const float* __restrict__ x, float* __restrict__ out, int B, float scale) {
    const float2* mp = (const float2*)m;
    const float2* xp = (const float2*)x;
    const float4* Lp = (const float4*)L;

    const int T = gridDim.x * blockDim.x;
    const int i = blockIdx.x * blockDim.x + threadIdx.x;
    const int Bm1 = B - 1;

    int r0 = i, r1 = i + T, r2 = i + 2 * T, r3 = i + 3 * T;
    int c0 = min(r0, Bm1), c1 = min(r1, Bm1), c2 = min(r2, Bm1), c3 = min(r3, Bm1);

    // issue all 12 loads up front (all coalesced)
    float2 ma = mp[c0], mb = mp[c1], mc = mp[c2], md = mp[c3];
    float2 xa = xp[c0], xb = xp[c1], xc = xp[c2], xd = xp[c3];
    float4 La = Lp[c0], Lb = Lp[c1], Lc = Lp[c2], Ld = Lp[c3];

    float s0 = row_logprob(ma.x, ma.y, xa.x, xa.y, La.x, La.z, La.w);
    float s1 = row_logprob(mb.x, mb.y, xb.x, xb.y, Lb.x, Lb.z, Lb.w);
    float s2 = row_logprob(mc.x, mc.y, xc.x, xc.y, Lc.x, Lc.z, Lc.w);
    float s3 = row_logprob(md.x, md.y, xd.x, xd.y, Ld.x, Ld.z, Ld.w);

    float local = (r0 < B ? s0 : 0.0f) + (r1 < B ? s1 : 0.0f)
                + (r2 < B ? s2 : 0.0f) + (r3 < B ? s3 : 0.0f);

    // wave-64 reduce (float)
    for (int off = 32; off > 0; off >>= 1)
        local += __shfl_down(local, off, 64);

    __shared__ float wsum[4];
    int lane = threadIdx.x & 63;
    int wid  = threadIdx.x >> 6;
    if (lane == 0) wsum[wid] = local;
    __syncthreads();
    if (threadIdx.x == 0) {
        float s = wsum[0] + wsum[1] + wsum[2] + wsum[3];
        atomicAdd(out, s * scale);   // scale = -1/B
    }
}

extern "C" void kernel_launch(void* const* d_in, const int* in_sizes, int n_in,
                              void* d_out, int out_size, void* d_ws, size_t ws_size,
                              hipStream_t stream) {
    const float* m = (const float*)d_in[0];
    const float* L = (const float*)d_in[1];
    const float* x = (const float*)d_in[2];
    float* out = (float*)d_out;

    int B = in_sizes[0] / 2;
    int block = 256;
    int threads_needed = (B + 3) / 4;
    int grid = (threads_needed + block - 1) / block;
    float scale = -1.0f / (float)B;

    hipMemsetAsync(out, 0, sizeof(float), stream);
    hipLaunchKernelGGL(galnll_kernel, dim3(grid), dim3(block), 0, stream,
                       m, L, x, out, B, scale);
}

// Round 5
// 18.462 us; speedup vs baseline: 2.1377x; 2.1377x over previous
//
#include <hip/hip_runtime.h>
#include <math.h>

#define LN2 0.6931471805599453f
#define C0  (-1.1447298858494002f)   // log(2) - log(2*pi)

__device__ __forceinline__ float flog2(float x) { return __builtin_amdgcn_logf(x); }
__device__ __forceinline__ float frcp(float x)  { return __builtin_amdgcn_rcpf(x); }

// log_prob for one row given m=(m0,m1), x=(x0,x1), L=[[a,0],[c,b]]
__device__ __forceinline__ float row_logprob(float m0, float m1, float x0, float x1,
                                             float a, float c, float b) {
    float ra = frcp(a), rb = frcp(b);
    // Cholesky solves: y = L^-1 m, w = L^-1 x
    float y0 = m0 * ra, y1 = (m1 - c * y0) * rb;
    float w0 = x0 * ra, w1 = (x1 - c * w0) * rb;
    float mSm = fmaf(y0, y0, y1 * y1);
    float xSx = fmaf(w0, w0, w1 * w1);
    float xSm = fmaf(w0, y0, w1 * y1);
    float ap = 2.0f + mSm;
    float z  = __builtin_amdgcn_sqrtf(ap * xSx);

    float l2ab = flog2(a) + flog2(b);       // 0.5*log2(det) = log2 a + log2 b
    float l2x  = flog2(xSx);
    float l2p  = flog2(ap);

    // ---- small branch (z <= 2), args clamped like the reference ----
    float zs = fminf(z, 2.0f);
    float t = zs * (1.0f / 3.75f); t *= t;
    float i1 = zs * fmaf(t, fmaf(t, fmaf(t, fmaf(t, fmaf(t, fmaf(t,
               0.00032411f, 0.00301532f), 0.02658733f), 0.15084934f),
               0.51498869f), 0.87890594f), 0.5f);
    float u = 0.5f * zs; u *= u;
    float ps = fmaf(u, fmaf(u, fmaf(u, fmaf(u, fmaf(u, fmaf(u,
               -0.00004686f, -0.00110404f), -0.01919402f), -0.18156897f),
               -0.67278579f), 0.15443144f), 1.0f);
    // ln(z/2) = ln2*(log2 z - 1), log2 z = 0.5*(l2p + l2x)
    float lnz_half = LN2 * fmaf(0.5f, l2p + l2x, -1.0f);
    float k1s = lnz_half * i1 + ps * frcp(zs);
    float lpS = LN2 * (l2ab + 0.5f * l2x - 0.5f * l2p + flog2(k1s));

    // ---- large branch (z > 2): -z - 0.5 ln z + ln(poly_l) merged ----
    float zl = fmaxf(z, 2.0f);
    float v = 2.0f * frcp(zl);
    float pl = fmaf(v, fmaf(v, fmaf(v, fmaf(v, fmaf(v, fmaf(v,
               -0.00068245f, 0.00325614f), -0.00780353f), 0.01504268f),
               -0.03655620f), 0.23498619f), 1.25331414f);
    float lpL = -z + LN2 * (l2ab + 0.25f * l2x - 0.75f * l2p + flog2(pl));

    float lp = (z <= 2.0f) ? lpS : lpL;
    return xSm + lp + C0;
}

// Block-linear, thread-strided: block owns rows [blockIdx*1024, +1024);
// thread tid handles base+tid, base+tid+256, base+tid+512, base+tid+768.
// Every float2/float4 load is lane-contiguous; block footprint is a
// contiguous 48 KB window across the three buffers.
__global__ __launch_bounds__(256) void galnll_kernel(
        const float* __restrict__ m, const float* __restrict__ L,
        const float* __restrict__ x, float* __restrict__ partials, int B) {
    const float2* mp = (const float2*)m;
    const float2* xp = (const float2*)x;
    const float4* Lp = (const float4*)L;

    const int base = blockIdx.x * 1024 + threadIdx.x;
    const int Bm1 = B - 1;

    int r0 = base, r1 = base + 256, r2 = base + 512, r3 = base + 768;
    int c0 = min(r0, Bm1), c1 = min(r1, Bm1), c2 = min(r2, Bm1), c3 = min(r3, Bm1);

    // issue all 12 loads up front (all coalesced)
    float2 ma = mp[c0], mb = mp[c1], mc = mp[c2], md = mp[c3];
    float2 xa = xp[c0], xb = xp[c1], xc = xp[c2], xd = xp[c3];
    float4 La = Lp[c0], Lb = Lp[c1], Lc = Lp[c2], Ld = Lp[c3];

    float s0 = row_logprob(ma.x, ma.y, xa.x, xa.y, La.x, La.z, La.w);
    float s1 = row_logprob(mb.x, mb.y, xb.x, xb.y, Lb.x, Lb.z, Lb.w);
    float s2 = row_logprob(mc.x, mc.y, xc.x, xc.y, Lc.x, Lc.z, Lc.w);
    float s3 = row_logprob(md.x, md.y, xd.x, xd.y, Ld.x, Ld.z, Ld.w);

    float local = (r0 < B ? s0 : 0.0f) + (r1 < B ? s1 : 0.0f)
                + (r2 < B ? s2 : 0.0f) + (r3 < B ? s3 : 0.0f);

    // wave-64 reduce (float)
    for (int off = 32; off > 0; off >>= 1)
        local += __shfl_down(local, off, 64);

    __shared__ float wsum[4];
    int lane = threadIdx.x & 63;
    int wid  = threadIdx.x >> 6;
    if (lane == 0) wsum[wid] = local;
    __syncthreads();
    if (threadIdx.x == 0)
        partials[blockIdx.x] = wsum[0] + wsum[1] + wsum[2] + wsum[3];
}

__global__ __launch_bounds__(256) void reduce_kernel(
        const float* __restrict__ partials, int n, float* __restrict__ out, int B) {
    double d = 0.0;
    for (int i = threadIdx.x; i < n; i += 256)
        d += (double)partials[i];
    for (int off = 32; off > 0; off >>= 1)
        d += __shfl_down(d, off, 64);
    __shared__ double wsum[4];
    int lane = threadIdx.x & 63;
    int wid  = threadIdx.x >> 6;
    if (lane == 0) wsum[wid] = d;
    __syncthreads();
    if (threadIdx.x == 0) {
        double s = wsum[0] + wsum[1] + wsum[2] + wsum[3];
        out[0] = (float)(-s / (double)B);
    }
}

extern "C" void kernel_launch(void* const* d_in, const int* in_sizes, int n_in,
                              void* d_out, int out_size, void* d_ws, size_t ws_size,
                              hipStream_t stream) {
    const float* m = (const float*)d_in[0];
    const float* L = (const float*)d_in[1];
    const float* x = (const float*)d_in[2];
    float* out = (float*)d_out;
    float* partials = (float*)d_ws;

    int B = in_sizes[0] / 2;
    int block = 256;
    int grid = (B + 1023) / 1024;   // 1024 rows per block

    hipLaunchKernelGGL(galnll_kernel, dim3(grid), dim3(block), 0, stream,
                       m, L, x, partials, B);
    hipLaunchKernelGGL(reduce_kernel, dim3(1), dim3(block), 0, stream,
                       partials, grid, out, B);
}